// Round 1
// baseline (728.214 us; speedup 1.0000x reference)
//
#include <hip/hip_runtime.h>
#include <hip/hip_bf16.h>

// Shapes: B=128, C=1000, D=300, L=40, H=100
// Workspace layout (floats):
//   wpack   [6][300][300]  @ 0        (tap-major, [j][d][f])
//   WcT     [600][300]     @ 540000
//   WdT     [300][100]     @ 720000
//   WmrT    [300][100]     @ 750000
//   WmcT    [300][100]     @ 780000
//   sysT    [300][128]     @ 810000
//   confsT  [300][128]     @ 848400
//   confvT  [300][128]     @ 886800
//   cand    [1000][300]    @ 925200
//   fu      [128][300]     @ 1225200
//   fuT     [300][128]     @ 1263600
//   y23     [1000]         @ 1302000
// total 1303000 floats = 5.212 MB

#define OFF_WCT    540000
#define OFF_WDT    720000
#define OFF_WMRT   750000
#define OFF_WMCT   780000
#define OFF_SYST   810000
#define OFF_CONFST 848400
#define OFF_CONFVT 886800
#define OFF_CAND   925200
#define OFF_FU     1225200
#define OFF_FUT    1263600
#define OFF_Y23    1302000

__device__ __forceinline__ float sigmoidf_fast(float x) {
    return 1.0f / (1.0f + __expf(-x));
}

// ---------------------------------------------------------------- K0: pack
__global__ void pack_kernel(const float* __restrict__ w1, const float* __restrict__ w2,
                            const float* __restrict__ w3, const float* __restrict__ Wc,
                            const float* __restrict__ Wd, const float* __restrict__ Wmr,
                            const float* __restrict__ Wmc, const float* __restrict__ sys,
                            const float* __restrict__ confs, const float* __restrict__ confv,
                            float* __restrict__ ws) {
    int idx = blockIdx.x * blockDim.x + threadIdx.x;
    float v;
    if (idx < 540000) {                    // wpack[j][d][f] = conv_w(j)[f][d][tap]
        int j = idx / 90000; int r = idx % 90000;
        int d = r / 300;     int f = r % 300;
        if (j == 0)      v = w1[f * 300 + d];
        else if (j == 1) v = w2[(f * 300 + d) * 2 + 0];
        else if (j == 2) v = w2[(f * 300 + d) * 2 + 1];
        else             v = w3[(f * 300 + d) * 3 + (j - 3)];
        ws[idx] = v;
    } else if (idx < 720000) {             // WcT[dd][f] = Wc[f][dd]
        int i = idx - OFF_WCT; int dd = i / 300, f = i % 300;
        ws[idx] = Wc[f * 600 + dd];
    } else if (idx < 750000) {             // WdT[f][j] = Wd[j][f]
        int i = idx - OFF_WDT; int f = i / 100, j = i % 100;
        ws[idx] = Wd[j * 300 + f];
    } else if (idx < 780000) {
        int i = idx - OFF_WMRT; int f = i / 100, j = i % 100;
        ws[idx] = Wmr[j * 300 + f];
    } else if (idx < 810000) {
        int i = idx - OFF_WMCT; int f = i / 100, j = i % 100;
        ws[idx] = Wmc[j * 300 + f];
    } else if (idx < 925200) {             // sysT/confsT/confvT [d][b] = src[b][d]
        int i = idx - OFF_SYST; int m = i / 38400; int r = i % 38400;
        int d = r / 128, b = r % 128;
        const float* src = (m == 0) ? sys : ((m == 1) ? confs : confv);
        ws[idx] = src[b * 300 + d];
    }
}

// ------------------------------------------------- K1: CNN encoder final_utt
__global__ __launch_bounds__(192) void conv_kernel(const float* __restrict__ utt,
        const float* __restrict__ wpack, const float* __restrict__ b1,
        const float* __restrict__ b2, const float* __restrict__ b3,
        float* __restrict__ fu, float* __restrict__ fuT) {
    __shared__ float xs[300 * 44 + 8];     // xs[d][t], stride 44 (16B-aligned rows)
    int b    = blockIdx.x >> 1;
    int half = blockIdx.x & 1;
    int tid  = threadIdx.x;
    const float* ub = utt + b * 12000;     // utt[b][t][d]
    for (int i = tid; i < 12000; i += 192) {
        int t = i / 300, d = i % 300;
        xs[d * 44 + t] = ub[i];
    }
    for (int i = tid; i < 1200; i += 192) { // zero pad t=40..43
        int d = i >> 2, t = 40 + (i & 3);
        xs[d * 44 + t] = 0.0f;
    }
    __syncthreads();
    if (tid >= 150) return;                 // no barriers below
    int f = half * 150 + tid;
    const float* w1p  = wpack + f;
    const float* w2ap = wpack +  90000 + f;
    const float* w2bp = wpack + 180000 + f;
    const float* w3ap = wpack + 270000 + f;
    const float* w3bp = wpack + 360000 + f;
    const float* w3cp = wpack + 450000 + f;
    float m1 = -1e30f, m2 = -1e30f, m3 = -1e30f;
    for (int t0 = 0; t0 < 40; t0 += 8) {
        float a1[8], a2[8], a3[8];
        #pragma unroll
        for (int j = 0; j < 8; j++) { a1[j] = 0.f; a2[j] = 0.f; a3[j] = 0.f; }
        for (int d = 0; d < 300; ++d) {
            const float* xr = xs + d * 44 + t0;
            float x[10];
            #pragma unroll
            for (int j = 0; j < 10; j++) x[j] = xr[j];
            float v1  = w1p[d * 300];
            float v2a = w2ap[d * 300], v2b = w2bp[d * 300];
            float v3a = w3ap[d * 300], v3b = w3bp[d * 300], v3c = w3cp[d * 300];
            #pragma unroll
            for (int j = 0; j < 8; j++) {
                a1[j] += x[j] * v1;
                a2[j] += x[j] * v2a + x[j + 1] * v2b;
                a3[j] += x[j] * v3a + x[j + 1] * v3b + x[j + 2] * v3c;
            }
        }
        #pragma unroll
        for (int j = 0; j < 8; j++) {
            int t = t0 + j;
            if (t < 40) m1 = fmaxf(m1, a1[j]);
            if (t < 39) m2 = fmaxf(m2, a2[j]);
            if (t < 38) m3 = fmaxf(m3, a3[j]);
        }
    }
    float r = fmaxf(m1 + b1[f], 0.f) + fmaxf(m2 + b2[f], 0.f) + fmaxf(m3 + b3[f], 0.f);
    fu[b * 300 + f]  = r;
    fuT[f * 128 + b] = r;
}

// ------------------------------------------------------------- K2: candidates
__global__ __launch_bounds__(320) void cand_kernel(const float* __restrict__ slot,
        const float* __restrict__ value, const float* __restrict__ WcT,
        const float* __restrict__ bc, float* __restrict__ cand) {
    int c0 = blockIdx.x * 4;
    int f  = threadIdx.x;
    if (f >= 300) return;
    float acc[4] = {0.f, 0.f, 0.f, 0.f};
    for (int dd = 0; dd < 300; ++dd) {
        float w = WcT[dd * 300 + f];
        #pragma unroll
        for (int r = 0; r < 4; r++) acc[r] += slot[(c0 + r) * 300 + dd] * w;
    }
    for (int dd = 0; dd < 300; ++dd) {
        float w = WcT[(300 + dd) * 300 + f];
        #pragma unroll
        for (int r = 0; r < 4; r++) acc[r] += value[(c0 + r) * 300 + dd] * w;
    }
    #pragma unroll
    for (int r = 0; r < 4; r++)
        cand[(c0 + r) * 300 + f] = sigmoidf_fast(acc[r] + bc[f]);
}

// ------------------------------------------------- K3: request/confirm gates
__global__ __launch_bounds__(128) void gates_kernel(const float* __restrict__ slot,
        const float* __restrict__ value, const float* __restrict__ sysT,
        const float* __restrict__ confsT, const float* __restrict__ confvT,
        const float* __restrict__ fu, const float* __restrict__ WmrT,
        const float* __restrict__ bmr, const float* __restrict__ WmcT,
        const float* __restrict__ bmc, const float* __restrict__ Wj,
        const float* __restrict__ bj, float* __restrict__ y23) {
    int c = blockIdx.x;
    int tid = threadIdx.x;
    __shared__ float spr[128], spc[128];
    __shared__ float smr[300], smc[300];
    __shared__ float red[128];
    {   // phase 1: P_r[b], P_c[b]
        float pr = 0.f, ps = 0.f, pv = 0.f;
        const float* se = slot + c * 300;
        const float* ve = value + c * 300;
        for (int d = 0; d < 300; ++d) {
            float s = se[d], v = ve[d];
            pr += s * sysT[d * 128 + tid];
            ps += s * confsT[d * 128 + tid];
            pv += v * confvT[d * 128 + tid];
        }
        spr[tid] = pr;
        spc[tid] = ps * pv;
    }
    __syncthreads();
    // phase 2: sigmoid(m_r[f]), sigmoid(m_c[f])
    for (int f = tid; f < 300; f += 128) {
        float mr = 0.f, mc = 0.f;
        for (int b = 0; b < 128; ++b) {
            float fv = fu[b * 300 + f];
            mr += spr[b] * fv;
            mc += spc[b] * fv;
        }
        smr[f] = sigmoidf_fast(mr);
        smc[f] = sigmoidf_fast(mc);
    }
    __syncthreads();
    // phase 3: H-layer + joint
    float contrib = 0.f;
    if (tid < 100) {
        float hr = 0.f, hc = 0.f;
        for (int ff = 0; ff < 300; ++ff) {
            hr += smr[ff] * WmrT[ff * 100 + tid];
            hc += smc[ff] * WmcT[ff * 100 + tid];
        }
        hr = sigmoidf_fast(hr + bmr[tid]);
        hc = sigmoidf_fast(hc + bmc[tid]);
        contrib = (hr + hc) * Wj[tid];
    }
    red[tid] = contrib;
    __syncthreads();
    for (int s = 64; s > 0; s >>= 1) {
        if (tid < s) red[tid] += red[tid + s];
        __syncthreads();
    }
    if (tid == 0) y23[c] = red[0] + 2.0f * bj[0];
}

// -------------------------------------- K4: main per-(b,c) MLP + final combine
__global__ __launch_bounds__(128) void main_kernel(const float* __restrict__ cand,
        const float* __restrict__ fuT, const float* __restrict__ WdT,
        const float* __restrict__ bd, const float* __restrict__ Wj,
        const float* __restrict__ bj, const float* __restrict__ y23,
        const float* __restrict__ ypast, float* __restrict__ out) {
    int c = blockIdx.x;
    int b = threadIdx.x;                 // 0..127
    const float* cc = cand + c * 300;    // wave-uniform reads
    float ppart = 0.f;
    #pragma unroll 1
    for (int pass = 0; pass < 2; ++pass) {
        int j0 = pass * 50;
        float h[50];
        #pragma unroll
        for (int r = 0; r < 50; r++) h[r] = 0.f;
        for (int f = 0; f < 300; ++f) {
            float s = cc[f] * fuT[f * 128 + b];
            s = sigmoidf_fast(s);
            const float* wr = WdT + f * 100 + j0;   // wave-uniform
            #pragma unroll
            for (int r = 0; r < 50; r++) h[r] += s * wr[r];
        }
        #pragma unroll
        for (int r = 0; r < 50; r++) {
            float hh = sigmoidf_fast(h[r] + bd[j0 + r]);
            ppart += hh * Wj[j0 + r];
        }
    }
    float y1 = ppart + bj[0];
    out[b * 1000 + c] = 0.5f * (y1 + y23[c]) + 0.5f * ypast[b * 1000 + c];
}

extern "C" void kernel_launch(void* const* d_in, const int* in_sizes, int n_in,
                              void* d_out, int out_size, void* d_ws, size_t ws_size,
                              hipStream_t stream) {
    const float* utt   = (const float*)d_in[0];
    const float* sys   = (const float*)d_in[1];
    const float* confs = (const float*)d_in[2];
    const float* confv = (const float*)d_in[3];
    const float* ypast = (const float*)d_in[4];
    const float* slot  = (const float*)d_in[5];
    const float* value = (const float*)d_in[6];
    const float* Wc    = (const float*)d_in[7];
    const float* bc    = (const float*)d_in[8];
    const float* w1    = (const float*)d_in[9];
    const float* b1    = (const float*)d_in[10];
    const float* w2    = (const float*)d_in[11];
    const float* b2    = (const float*)d_in[12];
    const float* w3    = (const float*)d_in[13];
    const float* b3    = (const float*)d_in[14];
    const float* Wd    = (const float*)d_in[15];
    const float* bd    = (const float*)d_in[16];
    const float* Wmr   = (const float*)d_in[17];
    const float* bmr   = (const float*)d_in[18];
    const float* Wmc   = (const float*)d_in[19];
    const float* bmc   = (const float*)d_in[20];
    const float* Wj    = (const float*)d_in[21];
    const float* bj    = (const float*)d_in[22];

    float* ws   = (float*)d_ws;
    float* out  = (float*)d_out;
    float* wpack  = ws;
    float* WcT    = ws + OFF_WCT;
    float* WdT    = ws + OFF_WDT;
    float* WmrT   = ws + OFF_WMRT;
    float* WmcT   = ws + OFF_WMCT;
    float* sysT   = ws + OFF_SYST;
    float* confsT = ws + OFF_CONFST;
    float* confvT = ws + OFF_CONFVT;
    float* cand   = ws + OFF_CAND;
    float* fu     = ws + OFF_FU;
    float* fuT    = ws + OFF_FUT;
    float* y23    = ws + OFF_Y23;

    pack_kernel <<<3615, 256, 0, stream>>>(w1, w2, w3, Wc, Wd, Wmr, Wmc, sys, confs, confv, ws);
    conv_kernel <<<256, 192, 0, stream>>>(utt, wpack, b1, b2, b3, fu, fuT);
    cand_kernel <<<250, 320, 0, stream>>>(slot, value, WcT, bc, cand);
    gates_kernel<<<1000, 128, 0, stream>>>(slot, value, sysT, confsT, confvT, fu,
                                           WmrT, bmr, WmcT, bmc, Wj, bj, y23);
    main_kernel <<<1000, 128, 0, stream>>>(cand, fuT, WdT, bd, Wj, bj, y23, ypast, out);
}

// Round 2
// 300.779 us; speedup vs baseline: 2.4211x; 2.4211x over previous
//
#include <hip/hip_runtime.h>
#include <hip/hip_bf16.h>

// Shapes: B=128, C=1000, D=300, L=40, H=100
// Workspace layout (BYTE offsets):
#define OFF_SYST   0          // sysT   [300][128] f32   153600 B
#define OFF_CONFST 153600     // confsT [300][128] f32
#define OFF_CONFVT 307200     // confvT [300][128] f32
#define OFF_WCT    460800     // WcT    [600][300] f32   720000 B
#define OFF_WMRT   1180800    // WmrT   [300][100] f32   120000 B
#define OFF_WMCT   1300800    // WmcT   [300][100] f32
#define OFF_CAND   1420800    // cand   [1000][300] f32  1200000 B
#define OFF_FU     2620800    // fu     [128][300] f32   153600 B
#define OFF_FUT    2774400    // fuT    [300][128] f32
#define OFF_Y23    2928000    // y23    [1000] f32       4000 B
#define OFF_BDP    2932000    // bdPad  [112] f32        448 B
#define OFF_WJP    2932448    // WjPad  [112] f32        448 B
#define OFF_XBF    2932992    // Xbf    [5120][320] bf16 3276800 B
#define OFF_WALLT  6209792    // WallT  [1920][320] bf16 1228800 B
#define OFF_WDPB   7438592    // WdPadbf[112][320] bf16  71680 B
#define OFF_PBF    7510272    // Pbf    [5120][1920] bf16 19660800 B
// total 27,171,072 bytes ~= 25.9 MB

typedef short bf16x8_t __attribute__((ext_vector_type(8)));
typedef float f32x4_t  __attribute__((ext_vector_type(4)));

__device__ __forceinline__ float sigmoidf_fast(float x) {
    return __builtin_amdgcn_rcpf(1.0f + __expf(-x));
}
__device__ __forceinline__ unsigned short f2bf(float x) {
    unsigned int u = __float_as_uint(x);
    unsigned int r = (u + 0x7FFFu + ((u >> 16) & 1u)) >> 16;
    return (unsigned short)r;
}
__device__ __forceinline__ float bf2f(unsigned short h) {
    return __uint_as_float(((unsigned int)h) << 16);
}

// ---------------------------------------------------------------- K0: pack
// element ranges:
//  [0,614400)        WallTbf[n=tap*320+f][k]   (bf16)
//  [614400,650240)   WdPadbf[j][k]             (bf16)
//  [650240,650352)   bdPad[112]                (f32)
//  [650352,650464)   WjPad[112]                (f32)
//  [650464,765664)   sysT/confsT/confvT [d][b] (f32)
//  [765664,795664)   WmrT[f][j]                (f32)
//  [795664,825664)   WmcT[f][j]                (f32)
//  [825664,1005664)  WcT[dd][f]                (f32)
__global__ void pack_kernel(const float* __restrict__ w1, const float* __restrict__ w2,
                            const float* __restrict__ w3, const float* __restrict__ Wc,
                            const float* __restrict__ Wd, const float* __restrict__ Wmr,
                            const float* __restrict__ Wmc, const float* __restrict__ sys,
                            const float* __restrict__ confs, const float* __restrict__ confv,
                            const float* __restrict__ bd, const float* __restrict__ Wj,
                            unsigned short* __restrict__ WallTbf,
                            unsigned short* __restrict__ WdPadbf,
                            float* __restrict__ bdPad, float* __restrict__ WjPad,
                            float* __restrict__ sysT, float* __restrict__ confsT,
                            float* __restrict__ confvT, float* __restrict__ WmrT,
                            float* __restrict__ WmcT, float* __restrict__ WcT) {
    int idx = blockIdx.x * blockDim.x + threadIdx.x;
    if (idx < 614400) {
        int n = idx / 320, k = idx % 320;
        int tap = n / 320 == 0 ? n / 320 : n / 320;  // tap below
        tap = n / 320;
        int f = n % 320;
        // n = tap*320+f  (tap = idx/102400)
        tap = idx / 102400;
        f = (idx - tap * 102400) / 320;
        k = idx % 320;
        float v = 0.0f;
        if (f < 300 && k < 300) {
            int fd = f * 300 + k;
            if (tap == 0)      v = w1[fd];
            else if (tap == 1) v = w2[fd * 2 + 0];
            else if (tap == 2) v = w2[fd * 2 + 1];
            else               v = w3[fd * 3 + (tap - 3)];
        }
        WallTbf[idx] = f2bf(v);
    } else if (idx < 650240) {
        int i = idx - 614400; int j = i / 320, k = i % 320;
        float v = (j < 100 && k < 300) ? Wd[j * 300 + k] : 0.0f;
        WdPadbf[i] = f2bf(v);
    } else if (idx < 650352) {
        int j = idx - 650240;
        bdPad[j] = (j < 100) ? bd[j] : 0.0f;
    } else if (idx < 650464) {
        int j = idx - 650352;
        WjPad[j] = (j < 100) ? Wj[j] : 0.0f;
    } else if (idx < 765664) {
        int i = idx - 650464; int m = i / 38400; int r = i % 38400;
        int d = r / 128, b = r % 128;
        const float* src = (m == 0) ? sys : ((m == 1) ? confs : confv);
        float* dst = (m == 0) ? sysT : ((m == 1) ? confsT : confvT);
        dst[r] = src[b * 300 + d];
    } else if (idx < 795664) {
        int i = idx - 765664; int f = i / 100, j = i % 100;
        WmrT[i] = Wmr[j * 300 + f];
    } else if (idx < 825664) {
        int i = idx - 795664; int f = i / 100, j = i % 100;
        WmcT[i] = Wmc[j * 300 + f];
    } else if (idx < 1005664) {
        int i = idx - 825664; int dd = i / 300, f = i % 300;
        WcT[i] = Wc[f * 600 + dd];
    }
}

// --------------------------------------------------- K0b: utt -> bf16 (padded K)
__global__ void xcvt_kernel(const float* __restrict__ utt, unsigned short* __restrict__ Xbf) {
    int idx = blockIdx.x * blockDim.x + threadIdx.x;   // 5120*320
    int m = idx / 320, k = idx % 320;
    float v = (k < 300) ? utt[m * 300 + k] : 0.0f;
    Xbf[idx] = f2bf(v);
}

// --------------------------------------------- K1: conv partials GEMM (MFMA)
// P[m][n] = sum_k X[m][k] * WallT[n][k];  M=5120, N=1920, K=320
__global__ __launch_bounds__(256, 2) void gemm1_kernel(const unsigned short* __restrict__ Xbf,
        const unsigned short* __restrict__ WallTbf, unsigned short* __restrict__ Pbf) {
    __shared__ __attribute__((aligned(16))) short As[128 * 40];
    __shared__ __attribute__((aligned(16))) short Bs[128 * 40];
    const int tid = threadIdx.x;
    const int m0 = blockIdx.x * 128;
    const int n0 = blockIdx.y * 128;
    const int lane = tid & 63;
    const int w = tid >> 6;          // 0..3
    const int wrow = w >> 1, wcol = w & 1;
    const int ln = lane & 15, lq = lane >> 4;

    f32x4_t acc[4][4];
    #pragma unroll
    for (int i = 0; i < 4; i++)
        #pragma unroll
        for (int j = 0; j < 4; j++) acc[i][j] = (f32x4_t){0.f, 0.f, 0.f, 0.f};

    for (int kk = 0; kk < 320; kk += 32) {
        // stage A[128][32], B[128][32] (row stride 40 bf16 in LDS)
        #pragma unroll
        for (int i = tid; i < 512; i += 256) {
            int row = i >> 2, q = i & 3;
            *(uint4*)(&As[row * 40 + q * 8]) =
                *(const uint4*)(Xbf + (m0 + row) * 320 + kk + q * 8);
        }
        #pragma unroll
        for (int i = tid; i < 512; i += 256) {
            int row = i >> 2, q = i & 3;
            *(uint4*)(&Bs[row * 40 + q * 8]) =
                *(const uint4*)(WallTbf + (n0 + row) * 320 + kk + q * 8);
        }
        __syncthreads();
        bf16x8_t a[4], b[4];
        #pragma unroll
        for (int mi = 0; mi < 4; mi++)
            a[mi] = *(const bf16x8_t*)(&As[(wrow * 64 + mi * 16 + ln) * 40 + lq * 8]);
        #pragma unroll
        for (int ni = 0; ni < 4; ni++)
            b[ni] = *(const bf16x8_t*)(&Bs[(wcol * 64 + ni * 16 + ln) * 40 + lq * 8]);
        #pragma unroll
        for (int mi = 0; mi < 4; mi++)
            #pragma unroll
            for (int ni = 0; ni < 4; ni++)
                acc[mi][ni] = __builtin_amdgcn_mfma_f32_16x16x32_bf16(a[mi], b[ni], acc[mi][ni], 0, 0, 0);
        __syncthreads();
    }
    // store C as bf16: row m = (lq*4+reg), col n = ln within each 16x16 tile
    #pragma unroll
    for (int mi = 0; mi < 4; mi++) {
        #pragma unroll
        for (int ni = 0; ni < 4; ni++) {
            int col = n0 + wcol * 64 + ni * 16 + ln;
            #pragma unroll
            for (int reg = 0; reg < 4; reg++) {
                int row = m0 + wrow * 64 + mi * 16 + lq * 4 + reg;
                Pbf[row * 1920 + col] = f2bf(acc[mi][ni][reg]);
            }
        }
    }
}

// ------------------------------------- K2: tap-combine + relu + maxpool -> fu
__global__ __launch_bounds__(320) void combine_kernel(const unsigned short* __restrict__ Pbf,
        const float* __restrict__ b1, const float* __restrict__ b2,
        const float* __restrict__ b3, float* __restrict__ fu, float* __restrict__ fuT) {
    int b = blockIdx.x;
    int f = threadIdx.x;
    if (f >= 300) return;
    const unsigned short* base = Pbf + (size_t)b * 40 * 1920;
    float m1 = -1e30f, m2 = -1e30f, m3 = -1e30f;
    float p1prev = 0.f, p3prev = 0.f, p3prev2 = 0.f, p4prev = 0.f;
    for (int t = 0; t < 40; ++t) {
        const unsigned short* r = base + t * 1920;
        float p0 = bf2f(r[f]);
        float p1 = bf2f(r[320 + f]);
        float p2 = bf2f(r[640 + f]);
        float p3 = bf2f(r[960 + f]);
        float p4 = bf2f(r[1280 + f]);
        float p5 = bf2f(r[1600 + f]);
        m1 = fmaxf(m1, p0);
        if (t >= 1) m2 = fmaxf(m2, p1prev + p2);
        if (t >= 2) m3 = fmaxf(m3, p3prev2 + p4prev + p5);
        p3prev2 = p3prev; p3prev = p3; p4prev = p4; p1prev = p1;
    }
    float r = fmaxf(m1 + b1[f], 0.f) + fmaxf(m2 + b2[f], 0.f) + fmaxf(m3 + b3[f], 0.f);
    fu[b * 300 + f]  = r;
    fuT[f * 128 + b] = r;
}

// ------------------------------------------------------------- K3: candidates
__global__ __launch_bounds__(320) void cand_kernel(const float* __restrict__ slot,
        const float* __restrict__ value, const float* __restrict__ WcT,
        const float* __restrict__ bc, float* __restrict__ cand) {
    int c0 = blockIdx.x * 4;
    int f  = threadIdx.x;
    if (f >= 300) return;
    float acc[4] = {0.f, 0.f, 0.f, 0.f};
    for (int dd = 0; dd < 300; ++dd) {
        float w = WcT[dd * 300 + f];
        #pragma unroll
        for (int r = 0; r < 4; r++) acc[r] += slot[(c0 + r) * 300 + dd] * w;
    }
    for (int dd = 0; dd < 300; ++dd) {
        float w = WcT[(300 + dd) * 300 + f];
        #pragma unroll
        for (int r = 0; r < 4; r++) acc[r] += value[(c0 + r) * 300 + dd] * w;
    }
    #pragma unroll
    for (int r = 0; r < 4; r++)
        cand[(c0 + r) * 300 + f] = sigmoidf_fast(acc[r] + bc[f]);
}

// ------------------------------------------------- K4: request/confirm gates
__global__ __launch_bounds__(128) void gates_kernel(const float* __restrict__ slot,
        const float* __restrict__ value, const float* __restrict__ sysT,
        const float* __restrict__ confsT, const float* __restrict__ confvT,
        const float* __restrict__ fu, const float* __restrict__ WmrT,
        const float* __restrict__ bmr, const float* __restrict__ WmcT,
        const float* __restrict__ bmc, const float* __restrict__ Wj,
        const float* __restrict__ bj, float* __restrict__ y23) {
    int c = blockIdx.x;
    int tid = threadIdx.x;
    __shared__ float spr[128], spc[128];
    __shared__ float smr[300], smc[300];
    __shared__ float red[128];
    {
        float pr = 0.f, ps = 0.f, pv = 0.f;
        const float* se = slot + c * 300;
        const float* ve = value + c * 300;
        for (int d = 0; d < 300; ++d) {
            float s = se[d], v = ve[d];
            pr += s * sysT[d * 128 + tid];
            ps += s * confsT[d * 128 + tid];
            pv += v * confvT[d * 128 + tid];
        }
        spr[tid] = pr;
        spc[tid] = ps * pv;
    }
    __syncthreads();
    for (int f = tid; f < 300; f += 128) {
        float mr = 0.f, mc = 0.f;
        for (int b = 0; b < 128; ++b) {
            float fv = fu[b * 300 + f];
            mr += spr[b] * fv;
            mc += spc[b] * fv;
        }
        smr[f] = sigmoidf_fast(mr);
        smc[f] = sigmoidf_fast(mc);
    }
    __syncthreads();
    float contrib = 0.f;
    if (tid < 100) {
        float hr = 0.f, hc = 0.f;
        for (int ff = 0; ff < 300; ++ff) {
            hr += smr[ff] * WmrT[ff * 100 + tid];
            hc += smc[ff] * WmcT[ff * 100 + tid];
        }
        hr = sigmoidf_fast(hr + bmr[tid]);
        hc = sigmoidf_fast(hc + bmc[tid]);
        contrib = (hr + hc) * Wj[tid];
    }
    red[tid] = contrib;
    __syncthreads();
    for (int s = 64; s > 0; s >>= 1) {
        if (tid < s) red[tid] += red[tid + s];
        __syncthreads();
    }
    if (tid == 0) y23[c] = red[0] + 2.0f * bj[0];
}

// --------------------- K5: fused main MLP GEMM (per-c) + epilogue + combine
// A[b][k] = sigmoid(cand[c][k]*fu[b][k]) (bf16, on-the-fly), B = WdPad[112][320]
__global__ __launch_bounds__(256, 2) void gemm2_kernel(const float* __restrict__ cand,
        const float* __restrict__ fuT, const unsigned short* __restrict__ WdPadbf,
        const float* __restrict__ bdPad, const float* __restrict__ WjPad,
        const float* __restrict__ bj, const float* __restrict__ y23,
        const float* __restrict__ ypast, float* __restrict__ out) {
    __shared__ __attribute__((aligned(16))) short As[128 * 40];
    __shared__ __attribute__((aligned(16))) short Bs[112 * 40];
    __shared__ float bdS[112], WjS[112], ybuf[128];
    const int c = blockIdx.x;
    const int tid = threadIdx.x;
    const int lane = tid & 63;
    const int w = tid >> 6;
    const int ln = lane & 15, lq = lane >> 4;
    const float* candRow = cand + c * 300;

    if (tid < 112) { bdS[tid] = bdPad[tid]; WjS[tid] = WjPad[tid]; }

    f32x4_t acc[2][7];
    #pragma unroll
    for (int mi = 0; mi < 2; mi++)
        #pragma unroll
        for (int ni = 0; ni < 7; ni++) acc[mi][ni] = (f32x4_t){0.f, 0.f, 0.f, 0.f};

    for (int kk = 0; kk < 320; kk += 32) {
        #pragma unroll
        for (int i = tid; i < 4096; i += 256) {
            int kl = i >> 7;         // 0..31
            int b  = i & 127;
            int k  = kk + kl;
            float v = 0.f;
            if (k < 300) v = sigmoidf_fast(candRow[k] * fuT[k * 128 + b]);
            As[b * 40 + kl] = (short)f2bf(v);
        }
        #pragma unroll
        for (int i = tid; i < 448; i += 256) {
            int row = i >> 2, q = i & 3;
            *(uint4*)(&Bs[row * 40 + q * 8]) =
                *(const uint4*)(WdPadbf + row * 320 + kk + q * 8);
        }
        __syncthreads();
        bf16x8_t a[2], b[7];
        #pragma unroll
        for (int mi = 0; mi < 2; mi++)
            a[mi] = *(const bf16x8_t*)(&As[(w * 32 + mi * 16 + ln) * 40 + lq * 8]);
        #pragma unroll
        for (int ni = 0; ni < 7; ni++)
            b[ni] = *(const bf16x8_t*)(&Bs[(ni * 16 + ln) * 40 + lq * 8]);
        #pragma unroll
        for (int mi = 0; mi < 2; mi++)
            #pragma unroll
            for (int ni = 0; ni < 7; ni++)
                acc[mi][ni] = __builtin_amdgcn_mfma_f32_16x16x32_bf16(a[mi], b[ni], acc[mi][ni], 0, 0, 0);
        __syncthreads();
    }
    // epilogue: h = sigmoid(acc + bd), psum = sum_n h*Wj
    float psum[2][4] = {{0.f, 0.f, 0.f, 0.f}, {0.f, 0.f, 0.f, 0.f}};
    #pragma unroll
    for (int mi = 0; mi < 2; mi++) {
        #pragma unroll
        for (int ni = 0; ni < 7; ni++) {
            int n = ni * 16 + ln;
            float bdv = bdS[n], wjv = WjS[n];
            #pragma unroll
            for (int reg = 0; reg < 4; reg++) {
                float h = sigmoidf_fast(acc[mi][ni][reg] + bdv);
                psum[mi][reg] += h * wjv;
            }
        }
    }
    #pragma unroll
    for (int mi = 0; mi < 2; mi++) {
        #pragma unroll
        for (int reg = 0; reg < 4; reg++) {
            float v = psum[mi][reg];
            v += __shfl_xor(v, 1);
            v += __shfl_xor(v, 2);
            v += __shfl_xor(v, 4);
            v += __shfl_xor(v, 8);
            if (ln == 0) ybuf[w * 32 + mi * 16 + lq * 4 + reg] = v;
        }
    }
    __syncthreads();
    if (tid < 128) {
        int b = tid;
        float y1 = ybuf[b] + bj[0];
        out[b * 1000 + c] = 0.5f * (y1 + y23[c]) + 0.5f * ypast[b * 1000 + c];
    }
}

extern "C" void kernel_launch(void* const* d_in, const int* in_sizes, int n_in,
                              void* d_out, int out_size, void* d_ws, size_t ws_size,
                              hipStream_t stream) {
    const float* utt   = (const float*)d_in[0];
    const float* sys   = (const float*)d_in[1];
    const float* confs = (const float*)d_in[2];
    const float* confv = (const float*)d_in[3];
    const float* ypast = (const float*)d_in[4];
    const float* slot  = (const float*)d_in[5];
    const float* value = (const float*)d_in[6];
    const float* Wc    = (const float*)d_in[7];
    const float* bc    = (const float*)d_in[8];
    const float* w1    = (const float*)d_in[9];
    const float* b1    = (const float*)d_in[10];
    const float* w2    = (const float*)d_in[11];
    const float* b2    = (const float*)d_in[12];
    const float* w3    = (const float*)d_in[13];
    const float* b3    = (const float*)d_in[14];
    const float* Wd    = (const float*)d_in[15];
    const float* bd    = (const float*)d_in[16];
    const float* Wmr   = (const float*)d_in[17];
    const float* bmr   = (const float*)d_in[18];
    const float* Wmc   = (const float*)d_in[19];
    const float* bmc   = (const float*)d_in[20];
    const float* Wj    = (const float*)d_in[21];
    const float* bj    = (const float*)d_in[22];

    char* wsb = (char*)d_ws;
    float* sysT   = (float*)(wsb + OFF_SYST);
    float* confsT = (float*)(wsb + OFF_CONFST);
    float* confvT = (float*)(wsb + OFF_CONFVT);
    float* WcT    = (float*)(wsb + OFF_WCT);
    float* WmrT   = (float*)(wsb + OFF_WMRT);
    float* WmcT   = (float*)(wsb + OFF_WMCT);
    float* cand   = (float*)(wsb + OFF_CAND);
    float* fu     = (float*)(wsb + OFF_FU);
    float* fuT    = (float*)(wsb + OFF_FUT);
    float* y23    = (float*)(wsb + OFF_Y23);
    float* bdPad  = (float*)(wsb + OFF_BDP);
    float* WjPad  = (float*)(wsb + OFF_WJP);
    unsigned short* Xbf     = (unsigned short*)(wsb + OFF_XBF);
    unsigned short* WallTbf = (unsigned short*)(wsb + OFF_WALLT);
    unsigned short* WdPadbf = (unsigned short*)(wsb + OFF_WDPB);
    unsigned short* Pbf     = (unsigned short*)(wsb + OFF_PBF);
    float* out = (float*)d_out;

    pack_kernel<<<3929, 256, 0, stream>>>(w1, w2, w3, Wc, Wd, Wmr, Wmc, sys, confs, confv,
                                          bd, Wj, WallTbf, WdPadbf, bdPad, WjPad,
                                          sysT, confsT, confvT, WmrT, WmcT, WcT);
    xcvt_kernel<<<6400, 256, 0, stream>>>(utt, Xbf);
    gemm1_kernel<<<dim3(40, 15), 256, 0, stream>>>(Xbf, WallTbf, Pbf);
    combine_kernel<<<128, 320, 0, stream>>>(Pbf, b1, b2, b3, fu, fuT);
    cand_kernel<<<250, 320, 0, stream>>>(slot, value, WcT, bc, cand);
    gates_kernel<<<1000, 128, 0, stream>>>(slot, value, sysT, confsT, confvT, fu,
                                           WmrT, bmr, WmcT, bmc, Wj, bj, y23);
    gemm2_kernel<<<1000, 256, 0, stream>>>(cand, fuT, WdPadbf, bdPad, WjPad,
                                           bj, y23, ypast, out);
}

// Round 3
// 220.060 us; speedup vs baseline: 3.3092x; 1.3668x over previous
//
#include <hip/hip_runtime.h>
#include <hip/hip_bf16.h>

// Shapes: B=128, C=1000, D=300, L=40, H=100
// Workspace layout (BYTE offsets, all 64-aligned):
#define OFF_SYST    0          // sysT   [300][128] f32  153600
#define OFF_CONFST  153600     // confsT [300][128] f32
#define OFF_CONFVT  307200     // confvT [300][128] f32
#define OFF_WMRT    460800     // WmrT   [300][100] f32  120000
#define OFF_WMCT    580800     // WmcT   [300][100] f32
#define OFF_FU      700800     // fu     [128][300] f32  153600
#define OFF_Y23     854400     // y23    [1000]     f32  4000
#define OFF_BDP     858432     // bdPad  [112]      f32  448
#define OFF_WJP     858880     // WjPad  [112]      f32  448
#define OFF_BCP     859392     // bcPad  [320]      f32  1280
#define OFF_XBF     860672     // Xbf    [5120][320]  bf16  3276800
#define OFF_WALLT   4137472    // WallT  [1920][320]  bf16  1228800
#define OFF_PBF     5366272    // Pbf    [5120][1920] bf16  19660800
#define OFF_FUBF    25027072   // fubf   [128][320]   bf16  81920
#define OFF_CATSV   25108992   // catsv  [1024][640]  bf16  1310720
#define OFF_WCPK    26419712   // WcPk   [320][640]   bf16  409600
#define OFF_CANDBF  26829312   // candbf [1024][320]  bf16  655360
#define OFF_WDFRAG  27484672   // WdFrag [10][7][64][8] bf16 (frag order) 71680
// total 27,556,352 B ~= 26.3 MB

typedef short bf16x8_t __attribute__((ext_vector_type(8)));
typedef float f32x4_t  __attribute__((ext_vector_type(4)));

__device__ __forceinline__ float sigmoidf_fast(float x) {
    return __builtin_amdgcn_rcpf(1.0f + __expf(-x));
}
__device__ __forceinline__ unsigned short f2bf(float x) {
    unsigned int u = __float_as_uint(x);
    unsigned int r = (u + 0x7FFFu + ((u >> 16) & 1u)) >> 16;
    return (unsigned short)r;
}
__device__ __forceinline__ float bf2f(unsigned short h) {
    return __uint_as_float(((unsigned int)h) << 16);
}

// ---------------------------------------------------------------- K0: pack
// element ranges:
//  [0,614400)          WallTbf[tap*320+f][k]        (bf16)
//  [614400,650240)     WdFrag (MFMA frag order)     (bf16)
//  [650240,650352)     bdPad[112]                   (f32)
//  [650352,650464)     WjPad[112]                   (f32)
//  [650464,650784)     bcPad[320]                   (f32)
//  [650784,765984)     sysT/confsT/confvT [d][b]    (f32)
//  [765984,795984)     WmrT[f][j]                   (f32)
//  [795984,825984)     WmcT[f][j]                   (f32)
//  [825984,1481344)    catsv[1024][640]             (bf16)
//  [1481344,1686144)   WcPk[320][640]               (bf16)
__global__ void pack_kernel(const float* __restrict__ w1, const float* __restrict__ w2,
                            const float* __restrict__ w3, const float* __restrict__ Wc,
                            const float* __restrict__ Wd, const float* __restrict__ Wmr,
                            const float* __restrict__ Wmc, const float* __restrict__ sys,
                            const float* __restrict__ confs, const float* __restrict__ confv,
                            const float* __restrict__ bd, const float* __restrict__ Wj,
                            const float* __restrict__ bc, const float* __restrict__ slot,
                            const float* __restrict__ value,
                            unsigned short* __restrict__ WallTbf,
                            unsigned short* __restrict__ WdFrag,
                            float* __restrict__ bdPad, float* __restrict__ WjPad,
                            float* __restrict__ bcPad,
                            float* __restrict__ sysT, float* __restrict__ confsT,
                            float* __restrict__ confvT, float* __restrict__ WmrT,
                            float* __restrict__ WmcT,
                            unsigned short* __restrict__ catsv,
                            unsigned short* __restrict__ WcPk) {
    int idx = blockIdx.x * blockDim.x + threadIdx.x;
    if (idx < 614400) {
        int tap = idx / 102400;
        int rem = idx - tap * 102400;
        int f = rem / 320, k = rem % 320;
        float v = 0.0f;
        if (f < 300 && k < 300) {
            int fd = f * 300 + k;
            if (tap == 0)      v = w1[fd];
            else if (tap == 1) v = w2[fd * 2 + 0];
            else if (tap == 2) v = w2[fd * 2 + 1];
            else               v = w3[fd * 3 + (tap - 3)];
        }
        WallTbf[idx] = f2bf(v);
    } else if (idx < 650240) {
        int i = idx - 614400;
        int entry = i >> 3, e = i & 7;
        int kt = entry / 448;
        int r = entry - kt * 448;
        int ni = r >> 6, lane = r & 63;
        int j = ni * 16 + (lane & 15);
        int k = kt * 32 + (lane >> 4) * 8 + e;
        float v = (j < 100 && k < 300) ? Wd[j * 300 + k] : 0.0f;
        WdFrag[i] = f2bf(v);
    } else if (idx < 650352) {
        int j = idx - 650240;
        bdPad[j] = (j < 100) ? bd[j] : 0.0f;
    } else if (idx < 650464) {
        int j = idx - 650352;
        WjPad[j] = (j < 100) ? Wj[j] : 0.0f;
    } else if (idx < 650784) {
        int j = idx - 650464;
        bcPad[j] = (j < 300) ? bc[j] : 0.0f;
    } else if (idx < 765984) {
        int i = idx - 650784; int m = i / 38400; int r = i % 38400;
        int d = r / 128, b = r % 128;
        const float* src = (m == 0) ? sys : ((m == 1) ? confs : confv);
        float* dst = (m == 0) ? sysT : ((m == 1) ? confsT : confvT);
        dst[r] = src[b * 300 + d];
    } else if (idx < 795984) {
        int i = idx - 765984; int f = i / 100, j = i % 100;
        WmrT[i] = Wmr[j * 300 + f];
    } else if (idx < 825984) {
        int i = idx - 795984; int f = i / 100, j = i % 100;
        WmcT[i] = Wmc[j * 300 + f];
    } else if (idx < 1481344) {
        int i = idx - 825984;
        int c = i / 640, k = i % 640;
        float v = 0.0f;
        if (c < 1000) {
            if (k < 300)                   v = slot[c * 300 + k];
            else if (k >= 320 && k < 620)  v = value[c * 300 + (k - 320)];
        }
        catsv[i] = f2bf(v);
    } else if (idx < 1686144) {
        int i = idx - 1481344;
        int f = i / 640, k = i % 640;
        float v = 0.0f;
        if (f < 300) {
            if (k < 300)                   v = Wc[f * 600 + k];
            else if (k >= 320 && k < 620)  v = Wc[f * 600 + 300 + (k - 320)];
        }
        WcPk[i] = f2bf(v);
    }
}

// --------------------------------------------------- K0b: utt -> bf16 (padded K)
__global__ void xcvt_kernel(const float* __restrict__ utt, unsigned short* __restrict__ Xbf) {
    int idx = blockIdx.x * blockDim.x + threadIdx.x;   // 5120*320
    int m = idx / 320, k = idx % 320;
    float v = (k < 300) ? utt[m * 300 + k] : 0.0f;
    Xbf[idx] = f2bf(v);
}

// --------------------------------------------- K1: conv partials GEMM (MFMA)
// P[m][n] = sum_k X[m][k] * WallT[n][k];  M=5120, N=1920, K=320
__global__ __launch_bounds__(256, 2) void gemm1_kernel(const unsigned short* __restrict__ Xbf,
        const unsigned short* __restrict__ WallTbf, unsigned short* __restrict__ Pbf) {
    __shared__ __attribute__((aligned(16))) short As[128 * 40];
    __shared__ __attribute__((aligned(16))) short Bs[128 * 40];
    const int tid = threadIdx.x;
    const int m0 = blockIdx.x * 128;
    const int n0 = blockIdx.y * 128;
    const int lane = tid & 63;
    const int w = tid >> 6;          // 0..3
    const int wrow = w >> 1, wcol = w & 1;
    const int ln = lane & 15, lq = lane >> 4;

    f32x4_t acc[4][4];
    #pragma unroll
    for (int i = 0; i < 4; i++)
        #pragma unroll
        for (int j = 0; j < 4; j++) acc[i][j] = (f32x4_t){0.f, 0.f, 0.f, 0.f};

    for (int kk = 0; kk < 320; kk += 32) {
        #pragma unroll
        for (int i = tid; i < 512; i += 256) {
            int row = i >> 2, q = i & 3;
            *(uint4*)(&As[row * 40 + q * 8]) =
                *(const uint4*)(Xbf + (m0 + row) * 320 + kk + q * 8);
        }
        #pragma unroll
        for (int i = tid; i < 512; i += 256) {
            int row = i >> 2, q = i & 3;
            *(uint4*)(&Bs[row * 40 + q * 8]) =
                *(const uint4*)(WallTbf + (n0 + row) * 320 + kk + q * 8);
        }
        __syncthreads();
        bf16x8_t a[4], b[4];
        #pragma unroll
        for (int mi = 0; mi < 4; mi++)
            a[mi] = *(const bf16x8_t*)(&As[(wrow * 64 + mi * 16 + ln) * 40 + lq * 8]);
        #pragma unroll
        for (int ni = 0; ni < 4; ni++)
            b[ni] = *(const bf16x8_t*)(&Bs[(wcol * 64 + ni * 16 + ln) * 40 + lq * 8]);
        #pragma unroll
        for (int mi = 0; mi < 4; mi++)
            #pragma unroll
            for (int ni = 0; ni < 4; ni++)
                acc[mi][ni] = __builtin_amdgcn_mfma_f32_16x16x32_bf16(a[mi], b[ni], acc[mi][ni], 0, 0, 0);
        __syncthreads();
    }
    #pragma unroll
    for (int mi = 0; mi < 4; mi++) {
        #pragma unroll
        for (int ni = 0; ni < 4; ni++) {
            int col = n0 + wcol * 64 + ni * 16 + ln;
            #pragma unroll
            for (int reg = 0; reg < 4; reg++) {
                int row = m0 + wrow * 64 + mi * 16 + lq * 4 + reg;
                Pbf[row * 1920 + col] = f2bf(acc[mi][ni][reg]);
            }
        }
    }
}

// ------------------------------------- K2: tap-combine + relu + maxpool -> fu
__global__ __launch_bounds__(320) void combine_kernel(const unsigned short* __restrict__ Pbf,
        const float* __restrict__ b1, const float* __restrict__ b2,
        const float* __restrict__ b3, float* __restrict__ fu,
        unsigned short* __restrict__ fubf) {
    int b = blockIdx.x;
    int f = threadIdx.x;                 // 0..319
    if (f >= 300) { fubf[b * 320 + f] = 0; return; }
    const unsigned short* base = Pbf + (size_t)b * 40 * 1920;
    float m1 = -1e30f, m2 = -1e30f, m3 = -1e30f;
    float p1prev = 0.f, p3prev = 0.f, p3prev2 = 0.f, p4prev = 0.f;
    for (int t = 0; t < 40; ++t) {
        const unsigned short* r = base + t * 1920;
        float p0 = bf2f(r[f]);
        float p1 = bf2f(r[320 + f]);
        float p2 = bf2f(r[640 + f]);
        float p3 = bf2f(r[960 + f]);
        float p4 = bf2f(r[1280 + f]);
        float p5 = bf2f(r[1600 + f]);
        m1 = fmaxf(m1, p0);
        if (t >= 1) m2 = fmaxf(m2, p1prev + p2);
        if (t >= 2) m3 = fmaxf(m3, p3prev2 + p4prev + p5);
        p3prev2 = p3prev; p3prev = p3; p4prev = p4; p1prev = p1;
    }
    float r = fmaxf(m1 + b1[f], 0.f) + fmaxf(m2 + b2[f], 0.f) + fmaxf(m3 + b3[f], 0.f);
    fu[b * 300 + f]   = r;
    fubf[b * 320 + f] = f2bf(r);
}

// ------------------------------------------- K3: candidates GEMM (MFMA, 64x64)
// cand[c][f] = sigmoid( sum_k catsv[c][k]*WcPk[f][k] + bc[f] );  M=1024,N=320,K=640
__global__ __launch_bounds__(256) void cand_gemm(const unsigned short* __restrict__ catsv,
        const unsigned short* __restrict__ WcPk, const float* __restrict__ bcPad,
        unsigned short* __restrict__ candbf) {
    __shared__ __attribute__((aligned(16))) short As[64 * 40];
    __shared__ __attribute__((aligned(16))) short Bs[64 * 40];
    const int tid = threadIdx.x;
    const int m0 = blockIdx.x * 64, n0 = blockIdx.y * 64;
    const int lane = tid & 63, w = tid >> 6;
    const int wr = w & 1, wc = w >> 1;
    const int ln = lane & 15, lq = lane >> 4;
    f32x4_t acc[2][2];
    #pragma unroll
    for (int i = 0; i < 2; i++)
        #pragma unroll
        for (int j = 0; j < 2; j++) acc[i][j] = (f32x4_t){0.f, 0.f, 0.f, 0.f};
    const int srow = tid >> 2, sq = tid & 3;
    for (int kk = 0; kk < 640; kk += 32) {
        *(uint4*)(&As[srow * 40 + sq * 8]) = *(const uint4*)(catsv + (m0 + srow) * 640 + kk + sq * 8);
        *(uint4*)(&Bs[srow * 40 + sq * 8]) = *(const uint4*)(WcPk  + (n0 + srow) * 640 + kk + sq * 8);
        __syncthreads();
        bf16x8_t a[2], b[2];
        #pragma unroll
        for (int mi = 0; mi < 2; mi++)
            a[mi] = *(const bf16x8_t*)(&As[(wr * 32 + mi * 16 + ln) * 40 + lq * 8]);
        #pragma unroll
        for (int ni = 0; ni < 2; ni++)
            b[ni] = *(const bf16x8_t*)(&Bs[(wc * 32 + ni * 16 + ln) * 40 + lq * 8]);
        #pragma unroll
        for (int mi = 0; mi < 2; mi++)
            #pragma unroll
            for (int ni = 0; ni < 2; ni++)
                acc[mi][ni] = __builtin_amdgcn_mfma_f32_16x16x32_bf16(a[mi], b[ni], acc[mi][ni], 0, 0, 0);
        __syncthreads();
    }
    #pragma unroll
    for (int mi = 0; mi < 2; mi++) {
        #pragma unroll
        for (int ni = 0; ni < 2; ni++) {
            int n = n0 + wc * 32 + ni * 16 + ln;
            float bcv = bcPad[n];
            #pragma unroll
            for (int reg = 0; reg < 4; reg++) {
                int cr = m0 + wr * 32 + mi * 16 + lq * 4 + reg;
                candbf[cr * 320 + n] = f2bf(sigmoidf_fast(acc[mi][ni][reg] + bcv));
            }
        }
    }
}

// ------------------------------------------------- K4: request/confirm gates
__global__ __launch_bounds__(128) void gates_kernel(const float* __restrict__ slot,
        const float* __restrict__ value, const float* __restrict__ sysT,
        const float* __restrict__ confsT, const float* __restrict__ confvT,
        const float* __restrict__ fu, const float* __restrict__ WmrT,
        const float* __restrict__ bmr, const float* __restrict__ WmcT,
        const float* __restrict__ bmc, const float* __restrict__ Wj,
        const float* __restrict__ bj, float* __restrict__ y23) {
    int c = blockIdx.x;
    int tid = threadIdx.x;
    __shared__ float spr[128], spc[128];
    __shared__ float smr[300], smc[300];
    __shared__ float red[128];
    {
        float pr = 0.f, ps = 0.f, pv = 0.f;
        const float* se = slot + c * 300;
        const float* ve = value + c * 300;
        for (int d = 0; d < 300; ++d) {
            float s = se[d], v = ve[d];
            pr += s * sysT[d * 128 + tid];
            ps += s * confsT[d * 128 + tid];
            pv += v * confvT[d * 128 + tid];
        }
        spr[tid] = pr;
        spc[tid] = ps * pv;
    }
    __syncthreads();
    for (int f = tid; f < 300; f += 128) {
        float mr = 0.f, mc = 0.f;
        for (int b = 0; b < 128; ++b) {
            float fv = fu[b * 300 + f];
            mr += spr[b] * fv;
            mc += spc[b] * fv;
        }
        smr[f] = sigmoidf_fast(mr);
        smc[f] = sigmoidf_fast(mc);
    }
    __syncthreads();
    float contrib = 0.f;
    if (tid < 100) {
        float hr = 0.f, hc = 0.f;
        for (int ff = 0; ff < 300; ++ff) {
            hr += smr[ff] * WmrT[ff * 100 + tid];
            hc += smc[ff] * WmcT[ff * 100 + tid];
        }
        hr = sigmoidf_fast(hr + bmr[tid]);
        hc = sigmoidf_fast(hc + bmc[tid]);
        contrib = (hr + hc) * Wj[tid];
    }
    red[tid] = contrib;
    __syncthreads();
    for (int s = 64; s > 0; s >>= 1) {
        if (tid < s) red[tid] += red[tid + s];
        __syncthreads();
    }
    if (tid == 0) y23[c] = red[0] + 2.0f * bj[0];
}

// --------------------- K5: fused main MLP GEMM (per-c), register A-frag gen
// A[b][k] = sigmoid(cand[c][k]*fu[b][k]) computed in registers; B pre-swizzled.
__global__ __launch_bounds__(256) void gemm2_kernel(const unsigned short* __restrict__ candbf,
        const unsigned short* __restrict__ fubf, const unsigned short* __restrict__ WdFrag,
        const float* __restrict__ bdPad, const float* __restrict__ WjPad,
        const float* __restrict__ bj, const float* __restrict__ y23,
        const float* __restrict__ ypast, float* __restrict__ out) {
    __shared__ __attribute__((aligned(16))) short Bs[2][3584];   // 7.2 KB x2
    __shared__ float bdS[112], WjS[112], ybuf[128];
    const int c = blockIdx.x;
    const int tid = threadIdx.x;
    const int lane = tid & 63, w = tid >> 6;
    const int ln = lane & 15, lq = lane >> 4;
    if (tid < 112) { bdS[tid] = bdPad[tid]; WjS[tid] = WjPad[tid]; }

    const unsigned short* candRow = candbf + c * 320;
    const unsigned short* fuR0 = fubf + (w * 32 + ln) * 320;
    const unsigned short* fuR1 = fuR0 + 16 * 320;

    f32x4_t acc[2][7];
    #pragma unroll
    for (int mi = 0; mi < 2; mi++)
        #pragma unroll
        for (int ni = 0; ni < 7; ni++) acc[mi][ni] = (f32x4_t){0.f, 0.f, 0.f, 0.f};

    // stage kt=0 (448 uint4)
    {
        const uint4* src = (const uint4*)(WdFrag);
        uint4* dst = (uint4*)&Bs[0][0];
        dst[tid] = src[tid];
        if (tid < 192) dst[tid + 256] = src[tid + 256];
    }
    __syncthreads();

    #pragma unroll
    for (int kt = 0; kt < 10; kt++) {
        if (kt < 9) {
            const uint4* src = (const uint4*)(WdFrag + (kt + 1) * 3584);
            uint4* dst = (uint4*)&Bs[(kt + 1) & 1][0];
            dst[tid] = src[tid];
            if (tid < 192) dst[tid + 256] = src[tid + 256];
        }
        const int k0 = kt * 32 + lq * 8;
        bf16x8_t cf  = *(const bf16x8_t*)(candRow + k0);
        bf16x8_t f0v = *(const bf16x8_t*)(fuR0 + k0);
        bf16x8_t f1v = *(const bf16x8_t*)(fuR1 + k0);
        bf16x8_t a0, a1;
        #pragma unroll
        for (int e = 0; e < 8; e += 2) {
            float cv0 = bf2f((unsigned short)cf[e]);
            float cv1 = bf2f((unsigned short)cf[e + 1]);
            float2 s0 = make_float2(sigmoidf_fast(cv0 * bf2f((unsigned short)f0v[e])),
                                    sigmoidf_fast(cv1 * bf2f((unsigned short)f0v[e + 1])));
            float2 s1 = make_float2(sigmoidf_fast(cv0 * bf2f((unsigned short)f1v[e])),
                                    sigmoidf_fast(cv1 * bf2f((unsigned short)f1v[e + 1])));
            __hip_bfloat162 p0 = __float22bfloat162_rn(s0);
            __hip_bfloat162 p1 = __float22bfloat162_rn(s1);
            ((unsigned int*)&a0)[e >> 1] = *(unsigned int*)&p0;
            ((unsigned int*)&a1)[e >> 1] = *(unsigned int*)&p1;
        }
        #pragma unroll
        for (int ni = 0; ni < 7; ni++) {
            bf16x8_t bfr = *(const bf16x8_t*)(&Bs[kt & 1][(ni * 64 + lane) * 8]);
            acc[0][ni] = __builtin_amdgcn_mfma_f32_16x16x32_bf16(a0, bfr, acc[0][ni], 0, 0, 0);
            acc[1][ni] = __builtin_amdgcn_mfma_f32_16x16x32_bf16(a1, bfr, acc[1][ni], 0, 0, 0);
        }
        __syncthreads();
    }

    // epilogue: h = sigmoid(acc + bd), psum = sum_j h*Wj
    float psum[2][4] = {{0.f, 0.f, 0.f, 0.f}, {0.f, 0.f, 0.f, 0.f}};
    #pragma unroll
    for (int mi = 0; mi < 2; mi++) {
        #pragma unroll
        for (int ni = 0; ni < 7; ni++) {
            int n = ni * 16 + ln;
            float bdv = bdS[n], wjv = WjS[n];
            #pragma unroll
            for (int reg = 0; reg < 4; reg++) {
                float h = sigmoidf_fast(acc[mi][ni][reg] + bdv);
                psum[mi][reg] += h * wjv;
            }
        }
    }
    #pragma unroll
    for (int mi = 0; mi < 2; mi++) {
        #pragma unroll
        for (int reg = 0; reg < 4; reg++) {
            float v = psum[mi][reg];
            v += __shfl_xor(v, 1);
            v += __shfl_xor(v, 2);
            v += __shfl_xor(v, 4);
            v += __shfl_xor(v, 8);
            if (ln == 0) ybuf[w * 32 + mi * 16 + lq * 4 + reg] = v;
        }
    }
    __syncthreads();
    if (tid < 128) {
        int b = tid;
        float y1 = ybuf[b] + bj[0];
        out[b * 1000 + c] = 0.5f * (y1 + y23[c]) + 0.5f * ypast[b * 1000 + c];
    }
}

extern "C" void kernel_launch(void* const* d_in, const int* in_sizes, int n_in,
                              void* d_out, int out_size, void* d_ws, size_t ws_size,
                              hipStream_t stream) {
    const float* utt   = (const float*)d_in[0];
    const float* sys   = (const float*)d_in[1];
    const float* confs = (const float*)d_in[2];
    const float* confv = (const float*)d_in[3];
    const float* ypast = (const float*)d_in[4];
    const float* slot  = (const float*)d_in[5];
    const float* value = (const float*)d_in[6];
    const float* Wc    = (const float*)d_in[7];
    const float* bc    = (const float*)d_in[8];
    const float* w1    = (const float*)d_in[9];
    const float* b1    = (const float*)d_in[10];
    const float* w2    = (const float*)d_in[11];
    const float* b2    = (const float*)d_in[12];
    const float* w3    = (const float*)d_in[13];
    const float* b3    = (const float*)d_in[14];
    const float* Wd    = (const float*)d_in[15];
    const float* bd    = (const float*)d_in[16];
    const float* Wmr   = (const float*)d_in[17];
    const float* bmr   = (const float*)d_in[18];
    const float* Wmc   = (const float*)d_in[19];
    const float* bmc   = (const float*)d_in[20];
    const float* Wj    = (const float*)d_in[21];
    const float* bj    = (const float*)d_in[22];

    char* wsb = (char*)d_ws;
    float* sysT   = (float*)(wsb + OFF_SYST);
    float* confsT = (float*)(wsb + OFF_CONFST);
    float* confvT = (float*)(wsb + OFF_CONFVT);
    float* WmrT   = (float*)(wsb + OFF_WMRT);
    float* WmcT   = (float*)(wsb + OFF_WMCT);
    float* fu     = (float*)(wsb + OFF_FU);
    float* y23    = (float*)(wsb + OFF_Y23);
    float* bdPad  = (float*)(wsb + OFF_BDP);
    float* WjPad  = (float*)(wsb + OFF_WJP);
    float* bcPad  = (float*)(wsb + OFF_BCP);
    unsigned short* Xbf     = (unsigned short*)(wsb + OFF_XBF);
    unsigned short* WallTbf = (unsigned short*)(wsb + OFF_WALLT);
    unsigned short* Pbf     = (unsigned short*)(wsb + OFF_PBF);
    unsigned short* fubf    = (unsigned short*)(wsb + OFF_FUBF);
    unsigned short* catsv   = (unsigned short*)(wsb + OFF_CATSV);
    unsigned short* WcPk    = (unsigned short*)(wsb + OFF_WCPK);
    unsigned short* candbf  = (unsigned short*)(wsb + OFF_CANDBF);
    unsigned short* WdFrag  = (unsigned short*)(wsb + OFF_WDFRAG);
    float* out = (float*)d_out;

    pack_kernel<<<6587, 256, 0, stream>>>(w1, w2, w3, Wc, Wd, Wmr, Wmc, sys, confs, confv,
                                          bd, Wj, bc, slot, value,
                                          WallTbf, WdFrag, bdPad, WjPad, bcPad,
                                          sysT, confsT, confvT, WmrT, WmcT, catsv, WcPk);
    xcvt_kernel<<<6400, 256, 0, stream>>>(utt, Xbf);
    gemm1_kernel<<<dim3(40, 15), 256, 0, stream>>>(Xbf, WallTbf, Pbf);
    combine_kernel<<<128, 320, 0, stream>>>(Pbf, b1, b2, b3, fu, fubf);
    cand_gemm<<<dim3(16, 5), 256, 0, stream>>>(catsv, WcPk, bcPad, candbf);
    gates_kernel<<<1000, 128, 0, stream>>>(slot, value, sysT, confsT, confvT, fu,
                                           WmrT, bmr, WmcT, bmc, Wj, bj, y23);
    gemm2_kernel<<<1000, 256, 0, stream>>>(candbf, fubf, WdFrag, bdPad, WjPad,
                                           bj, y23, ypast, out);
}